// Round 3
// baseline (397.491 us; speedup 1.0000x reference)
//
#include <hip/hip_runtime.h>
#include <math.h>

typedef float v2f __attribute__((ext_vector_type(2)));

#define B_SEQ 65536
#define T_SEQ 34
#define VOCAB 14
#define SEQS_PER_BLK 64
#define BLK_THREADS 576                  // 9 waves, all fully active
#define NBLK (B_SEQ / SEQS_PER_BLK)      // 1024
#define NSTATE (T_SEQ * VOCAB)           // 476 distinct (t, token) states
#define ESTRIDE 20                       // floats per table entry (80 B)
#define ENT_B 80
#define SROW_B (VOCAB * ENT_B)           // 1120 B per s-row

__device__ __forceinline__ void layernorm6(const float* x, const float* g,
                                           const float* bt, float* o) {
    float mu = (x[0] + x[1] + x[2] + x[3] + x[4] + x[5]) * (1.0f / 6.0f);
    float var = 0.0f;
#pragma unroll
    for (int i = 0; i < 6; ++i) { float d = x[i] - mu; var += d * d; }
    var *= (1.0f / 6.0f);
    float rs = __builtin_amdgcn_rsqf(var + 1e-5f);
#pragma unroll
    for (int i = 0; i < 6; ++i) o[i] = (x[i] - mu) * rs * g[i] + bt[i];
}

// packed layernorm over 3 feature pairs -> v_pk_* ops
__device__ __forceinline__ void ln6p(const v2f* x, const float* g,
                                     const float* bt, v2f* o) {
    v2f s2 = x[0] + x[1] + x[2];
    float mu = (s2.x + s2.y) * (1.0f / 6.0f);
    v2f d0 = x[0] - mu, d1 = x[1] - mu, d2 = x[2] - mu;
    v2f vv = d0 * d0 + d1 * d1 + d2 * d2;
    float var = (vv.x + vv.y) * (1.0f / 6.0f);
    float rs = __builtin_amdgcn_rsqf(var + 1e-5f);
    const v2f* g2 = (const v2f*)g;
    const v2f* b2 = (const v2f*)bt;
    o[0] = d0 * rs * g2[0] + b2[0];
    o[1] = d1 * rs * g2[1] + b2[1];
    o[2] = d2 * rs * g2[2] + b2[2];
}

// packed gelu: erf via A&S 7.1.26 (|eps| <= 1.5e-7)
__device__ __forceinline__ v2f gelu2(v2f s) {
    const float pc = 0.3275911f;
    const float a1 = 0.254829592f, a2 = -0.284496736f, a3 = 1.421413741f,
                a4 = -1.453152027f, a5 = 1.061405429f;
    v2f ax; ax.x = fabsf(s.x); ax.y = fabsf(s.y);
    v2f xe = ax * 0.70710678118654752f;
    v2f dn = xe * pc + 1.0f;
    v2f t;  t.x = __builtin_amdgcn_rcpf(dn.x); t.y = __builtin_amdgcn_rcpf(dn.y);
    v2f poly = ((((a5 * t + a4) * t + a3) * t + a2) * t + a1) * t;
    v2f ea = xe * xe * -1.4426950408889634f;
    v2f ee; ee.x = __builtin_amdgcn_exp2f(ea.x); ee.y = __builtin_amdgcn_exp2f(ea.y);
    v2f er = 1.0f - poly * ee;
    v2f es; es.x = copysignf(er.x, s.x); es.y = copysignf(er.y, s.y);
    return 0.5f * s * (1.0f + es);
}

__device__ __forceinline__ void epilogue_row(
    v2f dn, v2f a0, v2f a1, v2f a2, int tk, int t,
    const float* __restrict__ tok_emb, const float* __restrict__ pos_enc,
    const float* __restrict__ wo,
    const float* __restrict__ ln2_g, const float* __restrict__ ln2_b,
    const float* __restrict__ w1, const float* __restrict__ b1,
    const float* __restrict__ w2, const float* __restrict__ b2,
    const float* __restrict__ lnf_g, const float* __restrict__ lnf_b,
    const float* __restrict__ w_head, float* __restrict__ orow)
{
    v2f inv;
    inv.x = __builtin_amdgcn_rcpf(dn.x);
    inv.y = __builtin_amdgcn_rcpf(dn.y);
    v2f aox = a0 * inv, aoy = a1 * inv, aoz = a2 * inv;
    float ao[6] = {aox.x, aoy.x, aoz.x, aox.y, aoy.y, aoz.y};

    float x[6];
#pragma unroll
    for (int i = 0; i < 3; ++i) x[i] = tok_emb[tk * 3 + i];
#pragma unroll
    for (int i = 0; i < 3; ++i) x[3 + i] = pos_enc[t * 3 + i];

    // attn out proj + residual (packed over output pairs)
    const v2f* wo2 = (const v2f*)wo;
    v2f X2[3] = { {x[0], x[1]}, {x[2], x[3]}, {x[4], x[5]} };
#pragma unroll
    for (int i = 0; i < 6; ++i) {
        X2[0] += ao[i] * wo2[i * 3 + 0];
        X2[1] += ao[i] * wo2[i * 3 + 1];
        X2[2] += ao[i] * wo2[i * 3 + 2];
    }

    // FFN (packed)
    v2f H[3];
    ln6p(X2, ln2_g, ln2_b, H);
    float h[6] = {H[0].x, H[0].y, H[1].x, H[1].y, H[2].x, H[2].y};
    const v2f* w1v = (const v2f*)w1;
    const v2f* b1v = (const v2f*)b1;
    v2f F[3] = { b1v[0], b1v[1], b1v[2] };
#pragma unroll
    for (int i = 0; i < 6; ++i) {
        F[0] += h[i] * w1v[i * 3 + 0];
        F[1] += h[i] * w1v[i * 3 + 1];
        F[2] += h[i] * w1v[i * 3 + 2];
    }
    F[0] = gelu2(F[0]); F[1] = gelu2(F[1]); F[2] = gelu2(F[2]);
    float f[6] = {F[0].x, F[0].y, F[1].x, F[1].y, F[2].x, F[2].y};
    const v2f* w2v = (const v2f*)w2;
    const v2f* b2v = (const v2f*)b2;
    v2f X3[3] = { X2[0] + b2v[0], X2[1] + b2v[1], X2[2] + b2v[2] };
#pragma unroll
    for (int i = 0; i < 6; ++i) {
        X3[0] += f[i] * w2v[i * 3 + 0];
        X3[1] += f[i] * w2v[i * 3 + 1];
        X3[2] += f[i] * w2v[i * 3 + 2];
    }

    // final LN + head (packed over 7 output pairs)
    v2f XO[3];
    ln6p(X3, lnf_g, lnf_b, XO);
    float xo[6] = {XO[0].x, XO[0].y, XO[1].x, XO[1].y, XO[2].x, XO[2].y};
    const v2f* whv = (const v2f*)w_head;
    v2f O[7] = {{0,0},{0,0},{0,0},{0,0},{0,0},{0,0},{0,0}};
#pragma unroll
    for (int i = 0; i < 6; ++i) {
#pragma unroll
        for (int j = 0; j < 7; ++j) O[j] += xo[i] * whv[i * 7 + j];
    }
    v2f* op = (v2f*)orow;
#pragma unroll
    for (int j = 0; j < 7; ++j) op[j] = O[j];
}

// One thread handles NQ consecutive query rows (t = tbase..tbase+NQ-1) of one
// sequence. KV loads are shared across the NQ queries; the causal triangle is
// fully static (no runtime masks).
template <int NQ>
__device__ __forceinline__ void process(
    int c, const float* kvtab, const unsigned* pkrow,
    const float* __restrict__ tok_emb, const float* __restrict__ pos_enc,
    const float* __restrict__ wo,
    const float* __restrict__ ln2_g, const float* __restrict__ ln2_b,
    const float* __restrict__ w1, const float* __restrict__ b1,
    const float* __restrict__ w2, const float* __restrict__ b2,
    const float* __restrict__ lnf_g, const float* __restrict__ lnf_b,
    const float* __restrict__ w_head, float* __restrict__ orow0)
{
    const int tbase = (NQ == 4) ? (c << 2) : 32;
    const unsigned myw = pkrow[tbase >> 3];
    int tk[NQ];
#pragma unroll
    for (int r = 0; r < NQ; ++r)
        tk[r] = (int)((myw >> (((tbase & 7) + r) * 4)) & 15u);

    const char* kvb = (const char*)kvtab;

    // q fragments from the table (pre-scaled by 1/sqrt(3)*log2e)
    v2f qx[NQ], qy[NQ], qz[NQ];
#pragma unroll
    for (int r = 0; r < NQ; ++r) {
        const char* qp = kvb + ((tbase + r) * VOCAB + tk[r]) * ENT_B + 48;
        const float4 qa = *(const float4*)qp;
        const v2f   qb = *(const v2f*)(qp + 16);
        qx[r] = v2f{qa.x, qa.y}; qy[r] = v2f{qa.z, qa.w}; qz[r] = qb;
    }

    v2f den[NQ], A0[NQ], A1[NQ], A2[NQ];
#pragma unroll
    for (int r = 0; r < NQ; ++r) {
        den[r] = v2f{0.f, 0.f}; A0[r] = v2f{0.f, 0.f};
        A1[r] = v2f{0.f, 0.f};  A2[r] = v2f{0.f, 0.f};
    }

#define KV_SLOT(OFFB, TK, RMIN) {                                             \
    const char* ep_ = kvb + (OFFB) + (TK) * ENT_B;                            \
    const float4 ea = *(const float4*)(ep_);        /* k0x k1x k0y k1y */     \
    const float4 eb = *(const float4*)(ep_ + 16);   /* k0z k1z v0x v1x */     \
    const float4 ec = *(const float4*)(ep_ + 32);   /* v0y v1y v0z v1z */     \
    const v2f kx = {ea.x, ea.y}, ky = {ea.z, ea.w}, kz = {eb.x, eb.y};        \
    const v2f vx = {eb.z, eb.w}, vy = {ec.x, ec.y}, vz = {ec.z, ec.w};        \
    _Pragma("unroll")                                                         \
    for (int r = (RMIN); r < NQ; ++r) {                                       \
        v2f sc = qx[r] * kx + qy[r] * ky + qz[r] * kz;                        \
        v2f p;                                                                \
        p.x = __builtin_amdgcn_exp2f(sc.x);                                   \
        p.y = __builtin_amdgcn_exp2f(sc.y);                                   \
        den[r] += p;                                                          \
        A0[r] += p * vx; A1[r] += p * vy; A2[r] += p * vz;                    \
    } }

    const int Wfull = (NQ == 4) ? (c >> 1) : 4;   // complete all-query words
    unsigned pw = pkrow[0];
    int sb = 0;
    for (int w = 0; w < Wfull; ++w) {
        const unsigned pwn = pkrow[w + 1];        // prefetch next token word
        KV_SLOT(sb + 0 * SROW_B, (pw >>  0) & 15u, 0)
        KV_SLOT(sb + 1 * SROW_B, (pw >>  4) & 15u, 0)
        KV_SLOT(sb + 2 * SROW_B, (pw >>  8) & 15u, 0)
        KV_SLOT(sb + 3 * SROW_B, (pw >> 12) & 15u, 0)
        KV_SLOT(sb + 4 * SROW_B, (pw >> 16) & 15u, 0)
        KV_SLOT(sb + 5 * SROW_B, (pw >> 20) & 15u, 0)
        KV_SLOT(sb + 6 * SROW_B, (pw >> 24) & 15u, 0)
        KV_SLOT(sb + 7 * SROW_B, (pw >> 28) & 15u, 0)
        pw = pwn; sb += 8 * SROW_B;
    }
    // remainder word (== myw's word): per-nibble active-query set is static
    if (NQ == 4) {
        if (c & 1) {   // slots s = 4c-4 .. 4c+3
            KV_SLOT(sb + 0 * SROW_B, (pw >>  0) & 15u, 0)
            KV_SLOT(sb + 1 * SROW_B, (pw >>  4) & 15u, 0)
            KV_SLOT(sb + 2 * SROW_B, (pw >>  8) & 15u, 0)
            KV_SLOT(sb + 3 * SROW_B, (pw >> 12) & 15u, 0)
            KV_SLOT(sb + 4 * SROW_B, (pw >> 16) & 15u, 0)
            KV_SLOT(sb + 5 * SROW_B, (pw >> 20) & 15u, 1)
            KV_SLOT(sb + 6 * SROW_B, (pw >> 24) & 15u, 2)
            KV_SLOT(sb + 7 * SROW_B, (pw >> 28) & 15u, 3)
        } else {       // slots s = 4c .. 4c+3
            KV_SLOT(sb + 0 * SROW_B, (pw >>  0) & 15u, 0)
            KV_SLOT(sb + 1 * SROW_B, (pw >>  4) & 15u, 1)
            KV_SLOT(sb + 2 * SROW_B, (pw >>  8) & 15u, 2)
            KV_SLOT(sb + 3 * SROW_B, (pw >> 12) & 15u, 3)
        }
    } else {           // c == 8: t = {32,33}; slots 32,33
        KV_SLOT(sb + 0 * SROW_B, (pw >>  0) & 15u, 0)
        KV_SLOT(sb + 1 * SROW_B, (pw >>  4) & 15u, 1)
    }
#undef KV_SLOT

#pragma unroll
    for (int r = 0; r < NQ; ++r)
        epilogue_row(den[r], A0[r], A1[r], A2[r], tk[r], tbase + r,
                     tok_emb, pos_enc, wo, ln2_g, ln2_b, w1, b1, w2, b2,
                     lnf_g, lnf_b, w_head, orow0 + r * 14);
}

__global__ __launch_bounds__(BLK_THREADS, 7) void fused_tf_kernel(
    const int* __restrict__ idx,
    const float* __restrict__ tok_emb,
    const float* __restrict__ pos_enc,
    const float* __restrict__ wq,
    const float* __restrict__ wk,
    const float* __restrict__ wv,
    const float* __restrict__ wo,
    const float* __restrict__ ln1_g, const float* __restrict__ ln1_b,
    const float* __restrict__ ln2_g, const float* __restrict__ ln2_b,
    const float* __restrict__ w1,   const float* __restrict__ b1,
    const float* __restrict__ w2,   const float* __restrict__ b2,
    const float* __restrict__ lnf_g, const float* __restrict__ lnf_b,
    const float* __restrict__ w_head,
    float* __restrict__ out)
{
    // table entry (80 B, 20 floats): [0:11] kv head-interleaved pairs,
    // [12:17] q pairs pre-scaled by 1/sqrt(3)*log2e, [18:19] pad.
    // stride 20 banks: only tk/tk+8 alias (2-way = free), 16-B aligned.
    __shared__ __align__(16) float kvtab[NSTATE * ESTRIDE];   // 38.1 KB
    __shared__ unsigned pk_lds[SEQS_PER_BLK * 5];             // 1.3 KB

    const int tid = threadIdx.x;

    // ---- build (t,tok) -> (k,v,q) table ----
    if (tid < NSTATE) {
        const int e = tid;
        const int tt = e / VOCAB;
        const int v = e - tt * VOCAB;
        float x0[6];
#pragma unroll
        for (int i = 0; i < 3; ++i) x0[i] = tok_emb[v * 3 + i];
#pragma unroll
        for (int i = 0; i < 3; ++i) x0[3 + i] = pos_enc[tt * 3 + i];
        float xl[6];
        layernorm6(x0, ln1_g, ln1_b, xl);
        float kc[6], vc[6], qc[6];
        const float qs = 0.57735026918962576f * 1.4426950408889634f;
#pragma unroll
        for (int j = 0; j < 6; ++j) {
            kc[j] = xl[3] * wk[j] + xl[4] * wk[6 + j] + xl[5] * wk[12 + j];
            vc[j] = xl[0] * wv[j] + xl[1] * wv[6 + j] + xl[2] * wv[12 + j];
            qc[j] = (xl[3] * wq[j] + xl[4] * wq[6 + j] + xl[5] * wq[12 + j]) * qs;
        }
        float* dst = &kvtab[e * ESTRIDE];
        ((float4*)dst)[0] = make_float4(kc[0], kc[3], kc[1], kc[4]);
        ((float4*)dst)[1] = make_float4(kc[2], kc[5], vc[0], vc[3]);
        ((float4*)dst)[2] = make_float4(vc[1], vc[4], vc[2], vc[5]);
        ((float4*)dst)[3] = make_float4(qc[0], qc[3], qc[1], qc[4]);
        ((v2f*)dst)[8]    = v2f{qc[2], qc[5]};
    }
    // ---- pack tokens: 4 bits each, 8 per word, 5 words per sequence ----
    if (tid < SEQS_PER_BLK * 5) {
        const int sq = tid / 5;
        const int w  = tid - sq * 5;
        const int* p = idx + (size_t)blockIdx.x * (SEQS_PER_BLK * T_SEQ)
                       + sq * T_SEQ + w * 8;
        const int n = (w == 4) ? 2 : 8;
        unsigned pk = 0;
        for (int j = 0; j < n; ++j) pk |= ((unsigned)p[j]) << (4 * j);
        pk_lds[tid] = pk;
    }
    __syncthreads();

    // wave = chunk of 4 consecutive t (wave 8: the {32,33} pair); lane = seq.
    const int c   = tid >> 6;      // 0..8, wave-uniform
    const int seq = tid & 63;
    const int tbase = (c < 8) ? (c << 2) : 32;
    float* orow0 = out + ((size_t)(blockIdx.x * SEQS_PER_BLK + seq) * T_SEQ
                          + tbase) * 14;
    const unsigned* pkrow = &pk_lds[seq * 5];

    if (c < 8)
        process<4>(c, kvtab, pkrow, tok_emb, pos_enc, wo, ln2_g, ln2_b,
                   w1, b1, w2, b2, lnf_g, lnf_b, w_head, orow0);
    else
        process<2>(c, kvtab, pkrow, tok_emb, pos_enc, wo, ln2_g, ln2_b,
                   w1, b1, w2, b2, lnf_g, lnf_b, w_head, orow0);
}

extern "C" void kernel_launch(void* const* d_in, const int* in_sizes, int n_in,
                              void* d_out, int out_size, void* d_ws, size_t ws_size,
                              hipStream_t stream) {
    const int*   idx     = (const int*)d_in[0];
    const float* tok_emb = (const float*)d_in[1];
    const float* pos_enc = (const float*)d_in[2];
    const float* wq      = (const float*)d_in[3];
    const float* wk      = (const float*)d_in[4];
    const float* wv      = (const float*)d_in[5];
    const float* wo      = (const float*)d_in[6];
    const float* ln1_g   = (const float*)d_in[7];
    const float* ln1_b   = (const float*)d_in[8];
    const float* ln2_g   = (const float*)d_in[9];
    const float* ln2_b   = (const float*)d_in[10];
    const float* w1      = (const float*)d_in[11];
    const float* b1      = (const float*)d_in[12];
    const float* w2      = (const float*)d_in[13];
    const float* b2      = (const float*)d_in[14];
    const float* lnf_g   = (const float*)d_in[15];
    const float* lnf_b   = (const float*)d_in[16];
    const float* w_head  = (const float*)d_in[17];
    float* out = (float*)d_out;

    hipLaunchKernelGGL(fused_tf_kernel, dim3(NBLK), dim3(BLK_THREADS), 0, stream,
                       idx, tok_emb, pos_enc, wq, wk, wv, wo,
                       ln1_g, ln1_b, ln2_g, ln2_b, w1, b1, w2, b2,
                       lnf_g, lnf_b, w_head, out);
}

// Round 4
// 230.264 us; speedup vs baseline: 1.7262x; 1.7262x over previous
//
#include <hip/hip_runtime.h>
#include <math.h>

typedef float v2f __attribute__((ext_vector_type(2)));

#define B_SEQ 65536
#define T_SEQ 34
#define VOCAB 14
#define SEQS_PER_BLK 32
#define ACTIVE 544                       // 32 seqs * 17 antipodal pairs
#define BLK_THREADS 576                  // 9 waves
#define NBLK (B_SEQ / SEQS_PER_BLK)      // 2048
#define NSTATE (T_SEQ * VOCAB)           // 476 distinct (t, token) states
#define ESTRIDE 20                       // floats per table entry (80 B)
#define ENT_B 80
#define SROW_B (VOCAB * ENT_B)           // 1120 B per s-row

__device__ __forceinline__ void layernorm6(const float* x, const float* g,
                                           const float* bt, float* o) {
    float mu = (x[0] + x[1] + x[2] + x[3] + x[4] + x[5]) * (1.0f / 6.0f);
    float var = 0.0f;
#pragma unroll
    for (int i = 0; i < 6; ++i) { float d = x[i] - mu; var += d * d; }
    var *= (1.0f / 6.0f);
    float rs = __builtin_amdgcn_rsqf(var + 1e-5f);
#pragma unroll
    for (int i = 0; i < 6; ++i) o[i] = (x[i] - mu) * rs * g[i] + bt[i];
}

// packed layernorm over 3 feature pairs -> v_pk_* ops
__device__ __forceinline__ void ln6p(const v2f* x, const float* g,
                                     const float* bt, v2f* o) {
    v2f s2 = x[0] + x[1] + x[2];
    float mu = (s2.x + s2.y) * (1.0f / 6.0f);
    v2f d0 = x[0] - mu, d1 = x[1] - mu, d2 = x[2] - mu;
    v2f vv = d0 * d0 + d1 * d1 + d2 * d2;
    float var = (vv.x + vv.y) * (1.0f / 6.0f);
    float rs = __builtin_amdgcn_rsqf(var + 1e-5f);
    const v2f* g2 = (const v2f*)g;
    const v2f* b2 = (const v2f*)bt;
    o[0] = d0 * rs * g2[0] + b2[0];
    o[1] = d1 * rs * g2[1] + b2[1];
    o[2] = d2 * rs * g2[2] + b2[2];
}

// packed gelu: erf via A&S 7.1.26 (|eps| <= 1.5e-7)
__device__ __forceinline__ v2f gelu2(v2f s) {
    const float pc = 0.3275911f;
    const float a1 = 0.254829592f, a2 = -0.284496736f, a3 = 1.421413741f,
                a4 = -1.453152027f, a5 = 1.061405429f;
    v2f ax; ax.x = fabsf(s.x); ax.y = fabsf(s.y);
    v2f xe = ax * 0.70710678118654752f;
    v2f dn = xe * pc + 1.0f;
    v2f t;  t.x = __builtin_amdgcn_rcpf(dn.x); t.y = __builtin_amdgcn_rcpf(dn.y);
    v2f poly = ((((a5 * t + a4) * t + a3) * t + a2) * t + a1) * t;
    v2f ea = xe * xe * -1.4426950408889634f;
    v2f ee; ee.x = __builtin_amdgcn_exp2f(ea.x); ee.y = __builtin_amdgcn_exp2f(ea.y);
    v2f er = 1.0f - poly * ee;
    v2f es; es.x = copysignf(er.x, s.x); es.y = copysignf(er.y, s.y);
    return 0.5f * s * (1.0f + es);
}

__device__ __forceinline__ int nib5(unsigned k0, unsigned k1, unsigned k2,
                                    unsigned k3, unsigned k4, int pos) {
    unsigned a = (pos < 8)  ? k0 : k1;
    unsigned b = (pos < 24) ? k2 : k3;
    unsigned w = (pos < 16) ? a : b;
    w = (pos < 32) ? w : k4;
    return (int)((w >> ((pos & 7) * 4)) & 15u);
}

__device__ __forceinline__ void epilogue_row(
    v2f dn, v2f a0, v2f a1, v2f a2, int tk, int t,
    const float* __restrict__ tok_emb, const float* __restrict__ pos_enc,
    const float* __restrict__ wo,
    const float* __restrict__ ln2_g, const float* __restrict__ ln2_b,
    const float* __restrict__ w1, const float* __restrict__ b1,
    const float* __restrict__ w2, const float* __restrict__ b2,
    const float* __restrict__ lnf_g, const float* __restrict__ lnf_b,
    const float* __restrict__ w_head, float* __restrict__ orow)
{
    v2f inv;
    inv.x = __builtin_amdgcn_rcpf(dn.x);
    inv.y = __builtin_amdgcn_rcpf(dn.y);
    v2f aox = a0 * inv, aoy = a1 * inv, aoz = a2 * inv;
    float ao[6] = {aox.x, aoy.x, aoz.x, aox.y, aoy.y, aoz.y};

    float x[6];
#pragma unroll
    for (int i = 0; i < 3; ++i) x[i] = tok_emb[tk * 3 + i];
#pragma unroll
    for (int i = 0; i < 3; ++i) x[3 + i] = pos_enc[t * 3 + i];

    const v2f* wo2 = (const v2f*)wo;
    v2f X2[3] = { {x[0], x[1]}, {x[2], x[3]}, {x[4], x[5]} };
#pragma unroll
    for (int i = 0; i < 6; ++i) {
        X2[0] += ao[i] * wo2[i * 3 + 0];
        X2[1] += ao[i] * wo2[i * 3 + 1];
        X2[2] += ao[i] * wo2[i * 3 + 2];
    }

    v2f H[3];
    ln6p(X2, ln2_g, ln2_b, H);
    float h[6] = {H[0].x, H[0].y, H[1].x, H[1].y, H[2].x, H[2].y};
    const v2f* w1v = (const v2f*)w1;
    const v2f* b1v = (const v2f*)b1;
    v2f F[3] = { b1v[0], b1v[1], b1v[2] };
#pragma unroll
    for (int i = 0; i < 6; ++i) {
        F[0] += h[i] * w1v[i * 3 + 0];
        F[1] += h[i] * w1v[i * 3 + 1];
        F[2] += h[i] * w1v[i * 3 + 2];
    }
    F[0] = gelu2(F[0]); F[1] = gelu2(F[1]); F[2] = gelu2(F[2]);
    float f[6] = {F[0].x, F[0].y, F[1].x, F[1].y, F[2].x, F[2].y};
    const v2f* w2v = (const v2f*)w2;
    const v2f* b2v = (const v2f*)b2;
    v2f X3[3] = { X2[0] + b2v[0], X2[1] + b2v[1], X2[2] + b2v[2] };
#pragma unroll
    for (int i = 0; i < 6; ++i) {
        X3[0] += f[i] * w2v[i * 3 + 0];
        X3[1] += f[i] * w2v[i * 3 + 1];
        X3[2] += f[i] * w2v[i * 3 + 2];
    }

    v2f XO[3];
    ln6p(X3, lnf_g, lnf_b, XO);
    float xo[6] = {XO[0].x, XO[0].y, XO[1].x, XO[1].y, XO[2].x, XO[2].y};
    const v2f* whv = (const v2f*)w_head;
    v2f O[7] = {{0,0},{0,0},{0,0},{0,0},{0,0},{0,0},{0,0}};
#pragma unroll
    for (int i = 0; i < 6; ++i) {
#pragma unroll
        for (int j = 0; j < 7; ++j) O[j] += xo[i] * whv[i * 7 + j];
    }
    v2f* op = (v2f*)orow;
#pragma unroll
    for (int j = 0; j < 7; ++j) op[j] = O[j];
}

__global__ __launch_bounds__(BLK_THREADS, 5) void fused_tf_kernel(
    const int* __restrict__ idx,
    const float* __restrict__ tok_emb,
    const float* __restrict__ pos_enc,
    const float* __restrict__ wq,
    const float* __restrict__ wk,
    const float* __restrict__ wv,
    const float* __restrict__ wo,
    const float* __restrict__ ln1_g, const float* __restrict__ ln1_b,
    const float* __restrict__ ln2_g, const float* __restrict__ ln2_b,
    const float* __restrict__ w1,   const float* __restrict__ b1,
    const float* __restrict__ w2,   const float* __restrict__ b2,
    const float* __restrict__ lnf_g, const float* __restrict__ lnf_b,
    const float* __restrict__ w_head,
    float* __restrict__ out)
{
    // entry (80 B): [0:11] kv head-interleaved pairs, [12:17] q pairs
    // (pre-scaled by 1/sqrt(3)*log2e), [18:19] pad. stride 20 banks ->
    // only tk/tk+8 alias (2-way = free), 16-B aligned.
    __shared__ __align__(16) float kvtab[NSTATE * ESTRIDE];   // 38.1 KB
    __shared__ unsigned pk_lds[SEQS_PER_BLK * 5];             // 640 B

    const int tid = threadIdx.x;

    // ---- build (t,tok) -> (k,v,q) table ----
    if (tid < NSTATE) {
        const int e = tid;
        const int tt = e / VOCAB;
        const int v = e - tt * VOCAB;
        float x0[6];
#pragma unroll
        for (int i = 0; i < 3; ++i) x0[i] = tok_emb[v * 3 + i];
#pragma unroll
        for (int i = 0; i < 3; ++i) x0[3 + i] = pos_enc[tt * 3 + i];
        float xl[6];
        layernorm6(x0, ln1_g, ln1_b, xl);
        float kc[6], vc[6], qc[6];
        const float qs = 0.57735026918962576f * 1.4426950408889634f;
#pragma unroll
        for (int j = 0; j < 6; ++j) {
            kc[j] = xl[3] * wk[j] + xl[4] * wk[6 + j] + xl[5] * wk[12 + j];
            vc[j] = xl[0] * wv[j] + xl[1] * wv[6 + j] + xl[2] * wv[12 + j];
            qc[j] = (xl[3] * wq[j] + xl[4] * wq[6 + j] + xl[5] * wq[12 + j]) * qs;
        }
        float* dst = &kvtab[e * ESTRIDE];
        ((float4*)dst)[0] = make_float4(kc[0], kc[3], kc[1], kc[4]);
        ((float4*)dst)[1] = make_float4(kc[2], kc[5], vc[0], vc[3]);
        ((float4*)dst)[2] = make_float4(vc[1], vc[4], vc[2], vc[5]);
        ((float4*)dst)[3] = make_float4(qc[0], qc[3], qc[1], qc[4]);
        ((v2f*)dst)[8]    = v2f{qc[2], qc[5]};
    }
    // ---- pack tokens: 4 bits each, 8 per word, 5 words per sequence ----
    if (tid < SEQS_PER_BLK * 5) {
        const int sq = tid / 5;
        const int w  = tid - sq * 5;
        const int* p = idx + (size_t)blockIdx.x * (SEQS_PER_BLK * T_SEQ)
                       + sq * T_SEQ + w * 8;
        const int n = (w == 4) ? 2 : 8;
        unsigned pk = 0;
        for (int j = 0; j < n; ++j) pk |= ((unsigned)p[j]) << (4 * j);
        pk_lds[tid] = pk;
    }
    __syncthreads();

    if (tid >= ACTIVE) return;   // no further barriers

    // antipodal pairing: thread owns rows t=p and t=33-p of one sequence.
    // per-thread math units = (p+1)+(34-p) = 35: perfectly balanced waves.
    const int p   = tid >> 5;          // 0..16, uniform per 32-lane half
    const int seq = tid & 31;
    const int wu  = __builtin_amdgcn_readfirstlane(tid) >> 6;  // wave id 0..8

    // wave-uniform region bounds (scalar branches in the skeleton)
    const int both_end   = (wu < 8) ? 2 * wu      : 16;   // s<=both_end: A+B full
    const int aB_slot    = (wu < 8) ? 2 * wu + 1  : 1000; // A masked, B full
    const int b_start    = (wu < 8) ? 2 * wu + 2  : 17;   // B-only full region
    const int bfull_end  = (wu < 8) ? 32 - 2 * wu : 17;
    const int bmask_slot = (wu < 8) ? 33 - 2 * wu : 1000; // B masked

    const unsigned* pkr = &pk_lds[seq * 5];
    const unsigned pk0 = pkr[0], pk1 = pkr[1], pk2 = pkr[2],
                   pk3 = pkr[3], pk4 = pkr[4];

    const int tA = p, tB = 33 - p;
    const int tkA = nib5(pk0, pk1, pk2, pk3, pk4, tA);
    const int tkB = nib5(pk0, pk1, pk2, pk3, pk4, tB);

    const char* kvb = (const char*)kvtab;
    v2f qAx, qAy, qAz, qBx, qBy, qBz;
    {
        const char* qp = kvb + (tA * VOCAB + tkA) * ENT_B + 48;
        const float4 qa = *(const float4*)qp;
        qAx = v2f{qa.x, qa.y}; qAy = v2f{qa.z, qa.w};
        qAz = *(const v2f*)(qp + 16);
    }
    {
        const char* qp = kvb + (tB * VOCAB + tkB) * ENT_B + 48;
        const float4 qa = *(const float4*)qp;
        qBx = v2f{qa.x, qa.y}; qBy = v2f{qa.z, qa.w};
        qBz = *(const v2f*)(qp + 16);
    }

    v2f denA = {0,0}, A0A = {0,0}, A1A = {0,0}, A2A = {0,0};
    v2f denB = {0,0}, A0B = {0,0}, A1B = {0,0}, A2B = {0,0};

    // static word/shift selection: s_ is a literal in every expansion
#define PKW(s_) ((s_) < 8 ? pk0 : (s_) < 16 ? pk1 : (s_) < 24 ? pk2 : \
                 (s_) < 32 ? pk3 : pk4)
#define TKN(s_) ((int)((PKW(s_) >> (((s_) & 7) * 4)) & 15u))
#define LOADS(s_, EA, EB, EC) {                                               \
    const char* ep_ = kvb + (s_) * SROW_B + TKN(s_) * ENT_B;                  \
    EA = *(const float4*)(ep_);                                               \
    EB = *(const float4*)(ep_ + 16);                                          \
    EC = *(const float4*)(ep_ + 32); }

#define RMATH(EA, EB, EC, QX, QY, QZ, DEN, R0, R1, R2, VALID) {               \
    v2f sc_ = QX * v2f{EA.x, EA.y} + QY * v2f{EA.z, EA.w}                     \
            + QZ * v2f{EB.x, EB.y};                                           \
    v2f pp_;                                                                  \
    pp_.x = __builtin_amdgcn_exp2f(sc_.x);                                    \
    pp_.y = __builtin_amdgcn_exp2f(sc_.y);                                    \
    pp_.x = (VALID) ? pp_.x : 0.0f;                                           \
    pp_.y = (VALID) ? pp_.y : 0.0f;                                           \
    DEN += pp_;                                                               \
    R0 += pp_ * v2f{EB.z, EB.w};                                              \
    R1 += pp_ * v2f{EC.x, EC.y};                                              \
    R2 += pp_ * v2f{EC.z, EC.w}; }

#define MA(EA, EB, EC, VLD) RMATH(EA, EB, EC, qAx, qAy, qAz, denA, A0A, A1A, A2A, VLD)
#define MB(EA, EB, EC, VLD) RMATH(EA, EB, EC, qBx, qBy, qBz, denB, A0B, A1B, A2B, VLD)

#define SLOT_BOTH(s_) { float4 ea, eb, ec; LOADS(s_, ea, eb, ec)              \
    MA(ea, eb, ec, true) MB(ea, eb, ec, true) }
#define SLOT_AB(s_)   { float4 ea, eb, ec; LOADS(s_, ea, eb, ec)              \
    MA(ea, eb, ec, (s_) <= p) MB(ea, eb, ec, true) }
#define SLOT_B(s_)    { float4 ea, eb, ec; LOADS(s_, ea, eb, ec)              \
    MB(ea, eb, ec, true) }
#define SLOT_BM(s_)   { float4 ea, eb, ec; LOADS(s_, ea, eb, ec)              \
    MB(ea, eb, ec, (s_) <= tB) }

#define BOTH2(s_) { float4 ea0, eb0, ec0, ea1, eb1, ec1;                      \
    LOADS(s_, ea0, eb0, ec0) LOADS((s_) + 1, ea1, eb1, ec1)                   \
    MA(ea0, eb0, ec0, true) MB(ea0, eb0, ec0, true)                           \
    MA(ea1, eb1, ec1, true) MB(ea1, eb1, ec1, true) }
#define BON2(s_)  { float4 ea0, eb0, ec0, ea1, eb1, ec1;                      \
    LOADS(s_, ea0, eb0, ec0) LOADS((s_) + 1, ea1, eb1, ec1)                   \
    MB(ea0, eb0, ec0, true) MB(ea1, eb1, ec1, true) }

#pragma unroll
    for (int s = 0; s < 34; s += 2) {
        if (s + 1 <= both_end) {                       // pair fully A+B
            BOTH2(s)
        } else if (s >= b_start && s + 1 <= bfull_end) {  // pair fully B
            BON2(s)
        } else {
            // slot s
            if (s <= both_end)                       SLOT_BOTH(s)
            else if (s == aB_slot)                   SLOT_AB(s)
            else if (s >= b_start && s <= bfull_end) SLOT_B(s)
            else if (s == bmask_slot)                SLOT_BM(s)
            // slot s+1  (s+1 <= both_end is impossible here)
            if (s + 1 == aB_slot)                              SLOT_AB(s + 1)
            else if (s + 1 >= b_start && s + 1 <= bfull_end)   SLOT_B(s + 1)
            else if (s + 1 == bmask_slot)                      SLOT_BM(s + 1)
        }
    }

#undef BON2
#undef BOTH2
#undef SLOT_BM
#undef SLOT_B
#undef SLOT_AB
#undef SLOT_BOTH
#undef MB
#undef MA
#undef RMATH
#undef LOADS
#undef TKN
#undef PKW

    float* orow = out + ((size_t)(blockIdx.x * SEQS_PER_BLK + seq) * T_SEQ) * 14;
    epilogue_row(denA, A0A, A1A, A2A, tkA, tA, tok_emb, pos_enc, wo,
                 ln2_g, ln2_b, w1, b1, w2, b2, lnf_g, lnf_b, w_head,
                 orow + (size_t)tA * 14);
    epilogue_row(denB, A0B, A1B, A2B, tkB, tB, tok_emb, pos_enc, wo,
                 ln2_g, ln2_b, w1, b1, w2, b2, lnf_g, lnf_b, w_head,
                 orow + (size_t)tB * 14);
}

extern "C" void kernel_launch(void* const* d_in, const int* in_sizes, int n_in,
                              void* d_out, int out_size, void* d_ws, size_t ws_size,
                              hipStream_t stream) {
    const int*   idx     = (const int*)d_in[0];
    const float* tok_emb = (const float*)d_in[1];
    const float* pos_enc = (const float*)d_in[2];
    const float* wq      = (const float*)d_in[3];
    const float* wk      = (const float*)d_in[4];
    const float* wv      = (const float*)d_in[5];
    const float* wo      = (const float*)d_in[6];
    const float* ln1_g   = (const float*)d_in[7];
    const float* ln1_b   = (const float*)d_in[8];
    const float* ln2_g   = (const float*)d_in[9];
    const float* ln2_b   = (const float*)d_in[10];
    const float* w1      = (const float*)d_in[11];
    const float* b1      = (const float*)d_in[12];
    const float* w2      = (const float*)d_in[13];
    const float* b2      = (const float*)d_in[14];
    const float* lnf_g   = (const float*)d_in[15];
    const float* lnf_b   = (const float*)d_in[16];
    const float* w_head  = (const float*)d_in[17];
    float* out = (float*)d_out;

    hipLaunchKernelGGL(fused_tf_kernel, dim3(NBLK), dim3(BLK_THREADS), 0, stream,
                       idx, tok_emb, pos_enc, wq, wk, wv, wo,
                       ln1_g, ln1_b, ln2_g, ln2_b, w1, b1, w2, b2,
                       lnf_g, lnf_b, w_head, out);
}

// Round 6
// 213.628 us; speedup vs baseline: 1.8607x; 1.0779x over previous
//
#include <hip/hip_runtime.h>
#include <math.h>

typedef float v2f __attribute__((ext_vector_type(2)));

#define B_SEQ 65536
#define T_SEQ 34
#define VOCAB 14
#define SEQS_PER_BLK 30
#define ACTIVE (SEQS_PER_BLK * T_SEQ)    // 1020
#define BLK_THREADS 1024                  // 16 waves
#define NBLK ((B_SEQ + SEQS_PER_BLK - 1) / SEQS_PER_BLK)  // 2185 (last partial)
#define NSTATE (T_SEQ * VOCAB)            // 476 distinct (t, token) states
#define ESTRIDE 20                        // floats per table entry (80 B)
#define ENT_B 80
#define SROW_B (VOCAB * ENT_B)            // 1120 B per s-row

__device__ __forceinline__ void layernorm6(const float* x, const float* g,
                                           const float* bt, float* o) {
    float mu = (x[0] + x[1] + x[2] + x[3] + x[4] + x[5]) * (1.0f / 6.0f);
    float var = 0.0f;
#pragma unroll
    for (int i = 0; i < 6; ++i) { float d = x[i] - mu; var += d * d; }
    var *= (1.0f / 6.0f);
    float rs = __builtin_amdgcn_rsqf(var + 1e-5f);
#pragma unroll
    for (int i = 0; i < 6; ++i) o[i] = (x[i] - mu) * rs * g[i] + bt[i];
}

__device__ __forceinline__ void ln6p(const v2f* x, const float* g,
                                     const float* bt, v2f* o) {
    v2f s2 = x[0] + x[1] + x[2];
    float mu = (s2.x + s2.y) * (1.0f / 6.0f);
    v2f d0 = x[0] - mu, d1 = x[1] - mu, d2 = x[2] - mu;
    v2f vv = d0 * d0 + d1 * d1 + d2 * d2;
    float var = (vv.x + vv.y) * (1.0f / 6.0f);
    float rs = __builtin_amdgcn_rsqf(var + 1e-5f);
    const v2f* g2 = (const v2f*)g;
    const v2f* b2 = (const v2f*)bt;
    o[0] = d0 * rs * g2[0] + b2[0];
    o[1] = d1 * rs * g2[1] + b2[1];
    o[2] = d2 * rs * g2[2] + b2[2];
}

// packed gelu: erf via A&S 7.1.26 (|eps| <= 1.5e-7) — absmax proven in r2
__device__ __forceinline__ v2f gelu2(v2f s) {
    const float pc = 0.3275911f;
    const float a1 = 0.254829592f, a2 = -0.284496736f, a3 = 1.421413741f,
                a4 = -1.453152027f, a5 = 1.061405429f;
    v2f ax; ax.x = fabsf(s.x); ax.y = fabsf(s.y);
    v2f xe = ax * 0.70710678118654752f;
    v2f dn = xe * pc + 1.0f;
    v2f t;  t.x = __builtin_amdgcn_rcpf(dn.x); t.y = __builtin_amdgcn_rcpf(dn.y);
    v2f poly = ((((a5 * t + a4) * t + a3) * t + a2) * t + a1) * t;
    v2f ea = xe * xe * -1.4426950408889634f;
    v2f ee; ee.x = __builtin_amdgcn_exp2f(ea.x); ee.y = __builtin_amdgcn_exp2f(ea.y);
    v2f er = 1.0f - poly * ee;
    v2f es; es.x = copysignf(er.x, s.x); es.y = copysignf(er.y, s.y);
    return 0.5f * s * (1.0f + es);
}

__device__ __forceinline__ int nib5(unsigned k0, unsigned k1, unsigned k2,
                                    unsigned k3, unsigned k4, int pos) {
    unsigned a = (pos < 8)  ? k0 : k1;
    unsigned b = (pos < 24) ? k2 : k3;
    unsigned w = (pos < 16) ? a : b;
    w = (pos < 32) ? w : k4;
    return (int)((w >> ((pos & 7) * 4)) & 15u);
}

__device__ __forceinline__ void epilogue_row(
    v2f dn, v2f a0, v2f a1, v2f a2, int tk, int t,
    const float* __restrict__ tok_emb, const float* __restrict__ pos_enc,
    const float* __restrict__ wo,
    const float* __restrict__ ln2_g, const float* __restrict__ ln2_b,
    const float* __restrict__ w1, const float* __restrict__ b1,
    const float* __restrict__ w2, const float* __restrict__ b2,
    const float* __restrict__ lnf_g, const float* __restrict__ lnf_b,
    const float* __restrict__ w_head, float* __restrict__ orow)
{
    v2f inv;
    inv.x = __builtin_amdgcn_rcpf(dn.x);
    inv.y = __builtin_amdgcn_rcpf(dn.y);
    v2f aox = a0 * inv, aoy = a1 * inv, aoz = a2 * inv;
    float ao[6] = {aox.x, aoy.x, aoz.x, aox.y, aoy.y, aoz.y};

    float x[6];
#pragma unroll
    for (int i = 0; i < 3; ++i) x[i] = tok_emb[tk * 3 + i];
#pragma unroll
    for (int i = 0; i < 3; ++i) x[3 + i] = pos_enc[t * 3 + i];

    const v2f* wo2 = (const v2f*)wo;
    v2f X2[3] = { {x[0], x[1]}, {x[2], x[3]}, {x[4], x[5]} };
#pragma unroll
    for (int i = 0; i < 6; ++i) {
        X2[0] += ao[i] * wo2[i * 3 + 0];
        X2[1] += ao[i] * wo2[i * 3 + 1];
        X2[2] += ao[i] * wo2[i * 3 + 2];
    }

    v2f H[3];
    ln6p(X2, ln2_g, ln2_b, H);
    float h[6] = {H[0].x, H[0].y, H[1].x, H[1].y, H[2].x, H[2].y};
    const v2f* w1v = (const v2f*)w1;
    const v2f* b1v = (const v2f*)b1;
    v2f F[3] = { b1v[0], b1v[1], b1v[2] };
#pragma unroll
    for (int i = 0; i < 6; ++i) {
        F[0] += h[i] * w1v[i * 3 + 0];
        F[1] += h[i] * w1v[i * 3 + 1];
        F[2] += h[i] * w1v[i * 3 + 2];
    }
    F[0] = gelu2(F[0]); F[1] = gelu2(F[1]); F[2] = gelu2(F[2]);
    float f[6] = {F[0].x, F[0].y, F[1].x, F[1].y, F[2].x, F[2].y};
    const v2f* w2v = (const v2f*)w2;
    const v2f* b2v = (const v2f*)b2;
    v2f X3[3] = { X2[0] + b2v[0], X2[1] + b2v[1], X2[2] + b2v[2] };
#pragma unroll
    for (int i = 0; i < 6; ++i) {
        X3[0] += f[i] * w2v[i * 3 + 0];
        X3[1] += f[i] * w2v[i * 3 + 1];
        X3[2] += f[i] * w2v[i * 3 + 2];
    }

    v2f XO[3];
    ln6p(X3, lnf_g, lnf_b, XO);
    float xo[6] = {XO[0].x, XO[0].y, XO[1].x, XO[1].y, XO[2].x, XO[2].y};
    const v2f* whv = (const v2f*)w_head;
    v2f O[7] = {{0,0},{0,0},{0,0},{0,0},{0,0},{0,0},{0,0}};
#pragma unroll
    for (int i = 0; i < 6; ++i) {
#pragma unroll
        for (int j = 0; j < 7; ++j) O[j] += xo[i] * whv[i * 7 + j];
    }
    v2f* op = (v2f*)orow;
#pragma unroll
    for (int j = 0; j < 7; ++j) op[j] = O[j];
}

__global__ __launch_bounds__(BLK_THREADS, 8) void fused_tf_kernel(
    const int* __restrict__ idx,
    const float* __restrict__ tok_emb,
    const float* __restrict__ pos_enc,
    const float* __restrict__ wq,
    const float* __restrict__ wk,
    const float* __restrict__ wv,
    const float* __restrict__ wo,
    const float* __restrict__ ln1_g, const float* __restrict__ ln1_b,
    const float* __restrict__ ln2_g, const float* __restrict__ ln2_b,
    const float* __restrict__ w1,   const float* __restrict__ b1,
    const float* __restrict__ w2,   const float* __restrict__ b2,
    const float* __restrict__ lnf_g, const float* __restrict__ lnf_b,
    const float* __restrict__ w_head,
    float* __restrict__ out)
{
    // entry (80 B): [0:11] kv head-interleaved pairs, [12:17] q pairs
    // (pre-scaled by 1/sqrt(3)*log2e), [18:19] pad. stride 20 banks ->
    // only tk/tk+8 alias (2-way = free), 16-B aligned.
    __shared__ __align__(16) float kvtab[NSTATE * ESTRIDE];   // 38.1 KB
    __shared__ unsigned pk_lds[SEQS_PER_BLK * 5];             // 600 B

    const int tid = threadIdx.x;

    // ---- build (t,tok) -> (k,v,q) table (as in r2/r4; proven path) ----
    if (tid < NSTATE) {
        const int e = tid;
        const int tt = e / VOCAB;
        const int v = e - tt * VOCAB;
        float x0[6];
#pragma unroll
        for (int i = 0; i < 3; ++i) x0[i] = tok_emb[v * 3 + i];
#pragma unroll
        for (int i = 0; i < 3; ++i) x0[3 + i] = pos_enc[tt * 3 + i];
        float xl[6];
        layernorm6(x0, ln1_g, ln1_b, xl);
        float kc[6], vc[6], qc[6];
        const float qs = 0.57735026918962576f * 1.4426950408889634f;
#pragma unroll
        for (int j = 0; j < 6; ++j) {
            kc[j] = xl[3] * wk[j] + xl[4] * wk[6 + j] + xl[5] * wk[12 + j];
            vc[j] = xl[0] * wv[j] + xl[1] * wv[6 + j] + xl[2] * wv[12 + j];
            qc[j] = (xl[3] * wq[j] + xl[4] * wq[6 + j] + xl[5] * wq[12 + j]) * qs;
        }
        float* dst = &kvtab[e * ESTRIDE];
        ((float4*)dst)[0] = make_float4(kc[0], kc[3], kc[1], kc[4]);
        ((float4*)dst)[1] = make_float4(kc[2], kc[5], vc[0], vc[3]);
        ((float4*)dst)[2] = make_float4(vc[1], vc[4], vc[2], vc[5]);
        ((float4*)dst)[3] = make_float4(qc[0], qc[3], qc[1], qc[4]);
        ((v2f*)dst)[8]    = v2f{qc[2], qc[5]};
    }
    // ---- pack tokens: 4 bits each, 8 per word, 5 words per sequence ----
    if (tid < SEQS_PER_BLK * 5) {
        const int sq = tid / 5;
        const int w  = tid - sq * 5;
        const long long gseq = (long long)blockIdx.x * SEQS_PER_BLK + sq;
        unsigned pk = 0;
        if (gseq < B_SEQ) {
            const int* p = idx + gseq * T_SEQ + w * 8;
            const int n = (w == 4) ? 2 : 8;
            for (int j = 0; j < n; ++j) pk |= ((unsigned)p[j]) << (4 * j);
        }
        pk_lds[tid] = pk;
    }
    __syncthreads();

    if (tid >= ACTIVE) return;   // no further barriers

    // t-major mapping: descending t, 30 seqs per t-row.
    const int tp  = tid / 30;          // 0..33 (magic-mul)
    const int t   = 33 - tp;
    const int seq = tid - tp * 30;
    const long long b = (long long)blockIdx.x * SEQS_PER_BLK + seq;
    if (b >= B_SEQ) return;            // partial last block

    // wave-uniform t bounds (scalar)
    const int wbase = __builtin_amdgcn_readfirstlane(tid) & ~63;
    const int tmaxw = 33 - wbase / 30;
    int wlast = wbase + 63; if (wlast > ACTIVE - 1) wlast = ACTIVE - 1;
    const int tminw = 33 - wlast / 30;

    const unsigned* pkr = &pk_lds[seq * 5];
    const unsigned pk0 = pkr[0], pk1 = pkr[1], pk2 = pkr[2],
                   pk3 = pkr[3], pk4 = pkr[4];

    const int mytok = nib5(pk0, pk1, pk2, pk3, pk4, t);

    const char* kvb = (const char*)kvtab;
    v2f qx, qy, qz;
    {
        const char* qp = kvb + (t * VOCAB + mytok) * ENT_B + 48;
        const float4 qa = *(const float4*)qp;
        qx = v2f{qa.x, qa.y}; qy = v2f{qa.z, qa.w};
        qz = *(const v2f*)(qp + 16);
    }

    v2f den = {0, 0}, A0 = {0, 0}, A1 = {0, 0}, A2 = {0, 0};

    // static word/shift selection: s_ is a literal in every expansion
#define PKW(s_) ((s_) < 8 ? pk0 : (s_) < 16 ? pk1 : (s_) < 24 ? pk2 : \
                 (s_) < 32 ? pk3 : pk4)
#define TKN(s_) ((int)((PKW(s_) >> (((s_) & 7) * 4)) & 15u))
#define LOADS(s_, EA, EB, EC) {                                               \
    const char* ep_ = kvb + (s_) * SROW_B + TKN(s_) * ENT_B;                  \
    EA = *(const float4*)(ep_);                                               \
    EB = *(const float4*)(ep_ + 16);                                          \
    EC = *(const float4*)(ep_ + 32); }

#define KMATH(s_, EA, EB, EC, MASKED) {                                       \
    v2f sc_ = qx * v2f{EA.x, EA.y} + qy * v2f{EA.z, EA.w}                     \
            + qz * v2f{EB.x, EB.y};                                           \
    v2f pp_;                                                                  \
    pp_.x = __builtin_amdgcn_exp2f(sc_.x);                                    \
    pp_.y = __builtin_amdgcn_exp2f(sc_.y);                                    \
    if (MASKED) {                                                             \
        const bool ok_ = ((s_) <= t);                                         \
        pp_.x = ok_ ? pp_.x : 0.0f;                                           \
        pp_.y = ok_ ? pp_.y : 0.0f;                                           \
    }                                                                         \
    den += pp_;                                                               \
    A0 += pp_ * v2f{EB.z, EB.w};                                              \
    A1 += pp_ * v2f{EC.x, EC.y};                                              \
    A2 += pp_ * v2f{EC.z, EC.w}; }

#define SLOT2(sA, sB, MASKED) {                                               \
    float4 ea0, eb0, ec0, ea1, eb1, ec1;                                      \
    LOADS(sA, ea0, eb0, ec0)                                                  \
    LOADS(sB, ea1, eb1, ec1)                                                  \
    KMATH(sA, ea0, eb0, ec0, MASKED)                                          \
    KMATH(sB, ea1, eb1, ec1, MASKED) }

#define GROUP8(g_)                                                            \
    if (tminw >= (g_) * 8 + 7) {        /* straight-line, no masking */       \
        SLOT2((g_) * 8 + 0, (g_) * 8 + 1, 0)                                  \
        SLOT2((g_) * 8 + 2, (g_) * 8 + 3, 0)                                  \
        SLOT2((g_) * 8 + 4, (g_) * 8 + 5, 0)                                  \
        SLOT2((g_) * 8 + 6, (g_) * 8 + 7, 0)                                  \
    } else if (tmaxw >= (g_) * 8) {     /* boundary: 2-slot gating */         \
        SLOT2((g_) * 8 + 0, (g_) * 8 + 1, 1)                                  \
        if (tmaxw >= (g_) * 8 + 2) { SLOT2((g_) * 8 + 2, (g_) * 8 + 3, 1) }   \
        if (tmaxw >= (g_) * 8 + 4) { SLOT2((g_) * 8 + 4, (g_) * 8 + 5, 1) }   \
        if (tmaxw >= (g_) * 8 + 6) { SLOT2((g_) * 8 + 6, (g_) * 8 + 7, 1) }   \
    }

    GROUP8(0)
    GROUP8(1)
    GROUP8(2)
    GROUP8(3)
    if (tmaxw >= 32) { SLOT2(32, 33, 1) }

#undef GROUP8
#undef SLOT2
#undef KMATH
#undef LOADS
#undef TKN
#undef PKW

    float* orow = out + ((size_t)b * T_SEQ + t) * 14;
    epilogue_row(den, A0, A1, A2, mytok, t, tok_emb, pos_enc, wo,
                 ln2_g, ln2_b, w1, b1, w2, b2, lnf_g, lnf_b, w_head, orow);
}

extern "C" void kernel_launch(void* const* d_in, const int* in_sizes, int n_in,
                              void* d_out, int out_size, void* d_ws, size_t ws_size,
                              hipStream_t stream) {
    const int*   idx     = (const int*)d_in[0];
    const float* tok_emb = (const float*)d_in[1];
    const float* pos_enc = (const float*)d_in[2];
    const float* wq      = (const float*)d_in[3];
    const float* wk      = (const float*)d_in[4];
    const float* wv      = (const float*)d_in[5];
    const float* wo      = (const float*)d_in[6];
    const float* ln1_g   = (const float*)d_in[7];
    const float* ln1_b   = (const float*)d_in[8];
    const float* ln2_g   = (const float*)d_in[9];
    const float* ln2_b   = (const float*)d_in[10];
    const float* w1      = (const float*)d_in[11];
    const float* b1      = (const float*)d_in[12];
    const float* w2      = (const float*)d_in[13];
    const float* b2      = (const float*)d_in[14];
    const float* lnf_g   = (const float*)d_in[15];
    const float* lnf_b   = (const float*)d_in[16];
    const float* w_head  = (const float*)d_in[17];
    float* out = (float*)d_out;

    hipLaunchKernelGGL(fused_tf_kernel, dim3(NBLK), dim3(BLK_THREADS), 0, stream,
                       idx, tok_emb, pos_enc, wq, wk, wv, wo,
                       ln1_g, ln1_b, ln2_g, ln2_b, w1, b1, w2, b2,
                       lnf_g, lnf_b, w_head, out);
}